// Round 9
// baseline (306.362 us; speedup 1.0000x reference)
//
#include <hip/hip_runtime.h>

// Shapes (fixed): B=4, L=4096, DIM=1024, INNER=512, DSTATE=8, DTRANK=64, KSZ=3
// BL = 16384 rows. Chunked scan: 128 chunks x 32 steps, chunk-major summaries.

using bf16x8 = __attribute__((ext_vector_type(8))) short;
using f32x4  = __attribute__((ext_vector_type(4))) float;

__device__ __forceinline__ unsigned short f2bf(float f) {
  unsigned int u = __float_as_uint(f);
  u = u + 0x7fffu + ((u >> 16) & 1u);   // round-to-nearest-even
  return (unsigned short)(u >> 16);
}

// fast softplus: log1p(exp(x)) via hardware exp/log; exact passthrough for x>15
__device__ __forceinline__ float fsoftplus(float x) {
  return (x > 15.f) ? x : __logf(1.f + __expf(x));
}

__device__ __forceinline__ float ftanh(float x) {
  float v = fminf(fmaxf(x, -15.f), 15.f);
  float e = __expf(2.f * v);
  return (e - 1.f) / (e + 1.f);
}

// ---------------- unified prep: all fp32->bf16 conversions, ONE launch -----
// 4 float4 per thread (load-pipelined). grid = 4680:
// [0,4096) x | [4096,4352) W_in | [4352,4608) W_out | [4608,4616) W_dt |
// [4616,4680) W_xproj pad+cvt (per-short)
__device__ __forceinline__ void cvt4(const float* __restrict__ in,
                                     unsigned short* __restrict__ out, int i) {
  float4 v = ((const float4*)in)[i];
  ushort4 o;
  o.x = f2bf(v.x); o.y = f2bf(v.y); o.z = f2bf(v.z); o.w = f2bf(v.w);
  ((ushort4*)out)[i] = o;
}

__device__ __forceinline__ void cvt4x4(const float* __restrict__ in,
                                       unsigned short* __restrict__ out, int i0) {
  cvt4(in, out, i0);
  cvt4(in, out, i0 + 256);
  cvt4(in, out, i0 + 512);
  cvt4(in, out, i0 + 768);
}

__global__ __launch_bounds__(256) void prep_all(
    const float* __restrict__ x, const float* __restrict__ Win,
    const float* __restrict__ Wout, const float* __restrict__ Wdt,
    const float* __restrict__ Wxp,
    unsigned short* __restrict__ xbf, unsigned short* __restrict__ winbf,
    unsigned short* __restrict__ woutbf, unsigned short* __restrict__ wdbf,
    unsigned short* __restrict__ wxpbf) {
  int b = blockIdx.x, t = threadIdx.x;
  if (b < 4096)      cvt4x4(x,    xbf,    b * 1024 + t);
  else if (b < 4352) cvt4x4(Win,  winbf,  (b - 4096) * 1024 + t);
  else if (b < 4608) cvt4x4(Wout, woutbf, (b - 4352) * 1024 + t);
  else if (b < 4616) cvt4x4(Wdt,  wdbf,   (b - 4608) * 1024 + t);
  else {
#pragma unroll
    for (int k = 0; k < 4; ++k) {
      int i = (b - 4616) * 1024 + k * 256 + t;  // 128*512 shorts, rows 80..127=0
      int row = i >> 9;
      wxpbf[i] = (row < 80) ? f2bf(Wxp[i]) : (unsigned short)0;
    }
  }
}

// ========== m97-style GEMM cores (small shapes), fused epilogues ==========
// A: MxK row-major bf16, B: NxK row-major bf16 (B^T layout).

// proj GEMM: M=16384, N=128, K=512 with 64-ROW m-tiles (grid 256 -> all CUs;
// the old 128-row version ran 128 blocks on 256 CUs = half idle).
// 4 waves, wave tile 32x64, acc[2][4]. Same MFMA K-order and epilogue values
// as the 128-row version -> bit-identical outputs.
// Fused prep: cols 0-63 -> dtr bf16, 64-71 -> tanh -> bterm,
// 72-79 -> tanh -> cterm, 80-127 discarded.
__global__ __launch_bounds__(256) void gemm_proj64(
    const unsigned short* __restrict__ A,
    const unsigned short* __restrict__ B,
    unsigned short* __restrict__ dtr, float* __restrict__ bterm,
    float* __restrict__ cterm, int M, int N, int K) {
  __shared__ short As[64 * 32];    // 4KB
  __shared__ short Bs[128 * 32];   // 8KB
  const int m0 = blockIdx.x * 64;
  const int lane = threadIdx.x & 63;
  const int wv = threadIdx.x >> 6;
  const int wm = (wv >> 1) * 32;
  const int wn = (wv & 1) * 64;
  f32x4 acc[2][4] = {};
  const int arow = wv * 16 + (lane >> 2);    // A staging: 16 rows/wave
  const int brow = wv * 32 + (lane >> 2);    // B staging: 32 rows/wave
  const int koff = (lane & 3) * 8;
  const unsigned short* gA = A + (size_t)(m0 + arow) * K + koff;
  const unsigned short* gB = B + (size_t)brow * K + koff;
  short* lA = &As[(wv * 16) * 32];
  short* lB = &Bs[(wv * 32) * 32];
  const int r = lane & 15;
  const int q = lane >> 4;
  for (int k0 = 0; k0 < K; k0 += 32) {
    __syncthreads();
    __builtin_amdgcn_global_load_lds((const __attribute__((address_space(1))) void*)(const void*)gA,
                                     (__attribute__((address_space(3))) void*)(void*)lA, 16, 0, 0);
    __builtin_amdgcn_global_load_lds((const __attribute__((address_space(1))) void*)(const void*)gB,
                                     (__attribute__((address_space(3))) void*)(void*)lB, 16, 0, 0);
    __builtin_amdgcn_global_load_lds((const __attribute__((address_space(1))) void*)(const void*)(gB + 16 * K),
                                     (__attribute__((address_space(3))) void*)(void*)(lB + 16 * 32), 16, 0, 0);
    gA += 32; gB += 32;
    __syncthreads();
    bf16x8 av[2], bv[4];
#pragma unroll
    for (int i = 0; i < 2; ++i)
      av[i] = *(const bf16x8*)&As[(wm + i * 16 + r) * 32 + q * 8];
#pragma unroll
    for (int j = 0; j < 4; ++j)
      bv[j] = *(const bf16x8*)&Bs[(wn + j * 16 + r) * 32 + q * 8];
#pragma unroll
    for (int i = 0; i < 2; ++i)
#pragma unroll
      for (int j = 0; j < 4; ++j)
        acc[i][j] = __builtin_amdgcn_mfma_f32_16x16x32_bf16(av[i], bv[j], acc[i][j], 0, 0, 0);
  }
  // C/D layout: col = lane&15, row = (lane>>4)*4 + reg
#pragma unroll
  for (int i = 0; i < 2; ++i)
#pragma unroll
    for (int j = 0; j < 4; ++j) {
      const int col = wn + j * 16 + r;
#pragma unroll
      for (int t = 0; t < 4; ++t) {
        const int row = m0 + wm + i * 16 + q * 4 + t;
        float v = acc[i][j][t];
        if (col < 64)      dtr[(size_t)row * 64 + col] = f2bf(v);
        else if (col < 72) bterm[(size_t)row * 8 + (col - 64)] = ftanh(v);
        else if (col < 80) cterm[(size_t)row * 8 + (col - 72)] = ftanh(v);
      }
    }
}

// dt GEMM: M=16384, N=512, K=64. Fused: delta = clip(softplus(v + b_dt[n]),1e-4,1)
__global__ __launch_bounds__(256) void gemm_dt128(
    const unsigned short* __restrict__ A,
    const unsigned short* __restrict__ B,
    const float* __restrict__ bdt,
    float* __restrict__ C, int M, int N, int K) {
  __shared__ short As[128 * 32];
  __shared__ short Bs[128 * 32];
  const int m0 = blockIdx.x * 128;
  const int n0 = blockIdx.y * 128;
  const int lane = threadIdx.x & 63;
  const int wv = threadIdx.x >> 6;
  const int wm = (wv >> 1) * 64;
  const int wn = (wv & 1) * 64;
  f32x4 acc[4][4] = {};
  const int row_a = wv * 32 + (lane >> 2);
  const int koff = (lane & 3) * 8;
  const unsigned short* gA = A + (size_t)(m0 + row_a) * K + koff;
  const unsigned short* gB = B + (size_t)(n0 + row_a) * K + koff;
  short* lA = &As[(wv * 32) * 32];
  short* lB = &Bs[(wv * 32) * 32];
  const int r = lane & 15;
  const int q = lane >> 4;
  for (int k0 = 0; k0 < K; k0 += 32) {
    __syncthreads();
    __builtin_amdgcn_global_load_lds((const __attribute__((address_space(1))) void*)(const void*)gA,
                                     (__attribute__((address_space(3))) void*)(void*)lA, 16, 0, 0);
    __builtin_amdgcn_global_load_lds((const __attribute__((address_space(1))) void*)(const void*)(gA + 16 * K),
                                     (__attribute__((address_space(3))) void*)(void*)(lA + 16 * 32), 16, 0, 0);
    __builtin_amdgcn_global_load_lds((const __attribute__((address_space(1))) void*)(const void*)gB,
                                     (__attribute__((address_space(3))) void*)(void*)lB, 16, 0, 0);
    __builtin_amdgcn_global_load_lds((const __attribute__((address_space(1))) void*)(const void*)(gB + 16 * K),
                                     (__attribute__((address_space(3))) void*)(void*)(lB + 16 * 32), 16, 0, 0);
    gA += 32; gB += 32;
    __syncthreads();
    bf16x8 av[4], bv[4];
#pragma unroll
    for (int i = 0; i < 4; ++i)
      av[i] = *(const bf16x8*)&As[(wm + i * 16 + r) * 32 + q * 8];
#pragma unroll
    for (int j = 0; j < 4; ++j)
      bv[j] = *(const bf16x8*)&Bs[(wn + j * 16 + r) * 32 + q * 8];
#pragma unroll
    for (int i = 0; i < 4; ++i)
#pragma unroll
      for (int j = 0; j < 4; ++j)
        acc[i][j] = __builtin_amdgcn_mfma_f32_16x16x32_bf16(av[i], bv[j], acc[i][j], 0, 0, 0);
  }
#pragma unroll
  for (int j = 0; j < 4; ++j) {
    const int col = n0 + wn + j * 16 + r;
    const float bb = bdt[col];
#pragma unroll
    for (int i = 0; i < 4; ++i)
#pragma unroll
      for (int t = 0; t < 4; ++t) {
        float v = acc[i][j][t] + bb;
        float delta = fminf(fmaxf(fsoftplus(v), 1e-4f), 1.f);
        C[(size_t)(m0 + wm + i * 16 + q * 4 + t) * N + col] = delta;
      }
  }
}

// ================= 256x256 8-phase GEMM (big shapes) ======================
// Round-2 structure (measured 42-44us, 0 bank conflicts) — FROZEN.
// reads-at-phase-start -> stage -> [vmcnt] -> barrier -> lgkmcnt(0) -> MFMA.
// C[m,n] = sum_k A[m,k]*B[n,k].  BM=BN=256, BK=64, 8 waves, 128 KiB LDS.
// Slot layout [row(128)][col(64) bf16] with XOR swizzle col^=((row&7)<<3);
// linear gload_lds dest + pre-swizzled global source (involution).
__device__ __forceinline__ void g256_stage(short* lds, int slot,
    const unsigned short* sp, int ktIdx, int wvLds, int K) {
  const unsigned short* s = sp + ktIdx * 64;
  __builtin_amdgcn_global_load_lds((const __attribute__((address_space(1))) void*)s,
      (__attribute__((address_space(3))) void*)(lds + slot * 8192 + wvLds), 16, 0, 0);
  __builtin_amdgcn_global_load_lds((const __attribute__((address_space(1))) void*)(s + (size_t)64 * K),
      (__attribute__((address_space(3))) void*)(lds + slot * 8192 + 4096 + wvLds), 16, 0, 0);
}

template <int PAR, int MH, int NHLO, bool RA, bool RB, int SSLOT, bool VM, bool HINT>
__device__ __forceinline__ void g256_phase(
    short* lds, int aSlotOff, int bSlotOff, int aoff, int boff, int wvLds,
    bf16x8 (&av)[4][2], bf16x8 (&bv)[4][2], f32x4 (&acc)[8][4],
    const unsigned short* sp, int ktIdx, int K) {
  if (RA) {
#pragma unroll
    for (int ii = 0; ii < 4; ++ii) {
      av[ii][0] = *(const bf16x8*)&lds[PAR * 4 * 8192 + aSlotOff + MH * 4096 + ii * 1024 + aoff];
      av[ii][1] = *(const bf16x8*)&lds[PAR * 4 * 8192 + aSlotOff + MH * 4096 + ii * 1024 + (aoff ^ 32)];
    }
  }
  if (RB) {
#pragma unroll
    for (int jj = 0; jj < 2; ++jj) {
      bv[NHLO + jj][0] = *(const bf16x8*)&lds[(PAR * 4 + 2) * 8192 + bSlotOff + (NHLO + jj) * 1024 + boff];
      bv[NHLO + jj][1] = *(const bf16x8*)&lds[(PAR * 4 + 2) * 8192 + bSlotOff + (NHLO + jj) * 1024 + (boff ^ 32)];
    }
  }
  g256_stage(lds, SSLOT, sp, ktIdx, wvLds, K);
  if (HINT) asm volatile("s_waitcnt lgkmcnt(8)");
  if (VM) asm volatile("s_waitcnt vmcnt(4)" ::: "memory");
  __builtin_amdgcn_s_barrier();
  asm volatile("s_waitcnt lgkmcnt(0)" ::: "memory");
  __builtin_amdgcn_s_setprio(1);
#pragma unroll
  for (int ii = 0; ii < 4; ++ii)
#pragma unroll
    for (int jj = 0; jj < 2; ++jj) {
      acc[MH * 4 + ii][NHLO + jj] = __builtin_amdgcn_mfma_f32_16x16x32_bf16(
          av[ii][0], bv[NHLO + jj][0], acc[MH * 4 + ii][NHLO + jj], 0, 0, 0);
      acc[MH * 4 + ii][NHLO + jj] = __builtin_amdgcn_mfma_f32_16x16x32_bf16(
          av[ii][1], bv[NHLO + jj][1], acc[MH * 4 + ii][NHLO + jj], 0, 0, 0);
    }
  __builtin_amdgcn_s_setprio(0);
  __builtin_amdgcn_s_barrier();
}

__global__ __launch_bounds__(512, 2) void gemm256_bt(
    const unsigned short* __restrict__ A,
    const unsigned short* __restrict__ B,
    float* __restrict__ C, int M, int N, int K) {
  __shared__ short lds[8 * 8192];  // 128 KiB
  const int nmt = M >> 8;
  const int bid = blockIdx.x;
  // XCD swizzle for A-panel reuse: each XCD owns (nmt/8) m-tiles x ALL
  // n-tiles, so the 4 blocks sharing an A panel are co-resident on ONE XCD.
  const int g = nmt >> 3;
  const int xcd = bid & 7;
  const int loc = bid >> 3;
  const int mtile = xcd * g + (loc % g);
  const int ntile = loc / g;
  const int m0 = mtile << 8, n0 = ntile << 8;
  const int tid = threadIdx.x;
  const int w = tid >> 6, lane = tid & 63;
  const int r = lane & 15, q = lane >> 4;
  const int wrow = w >> 2, wcol = w & 3;
  // staging: dest row tid>>3, stored col (tid&7)*8 (linear); source col is
  // the swizzle-inverse (XOR involution), stays in the same 128-B line:
  const int srow = tid >> 3;
  const int scol = ((tid & 7) ^ (srow & 7)) << 3;
  const unsigned short* pA0 = A + (size_t)(m0 + srow) * K + scol;
  const unsigned short* pA1 = A + (size_t)(m0 + 128 + srow) * K + scol;
  const unsigned short* pB0 = B + (size_t)(n0 + srow) * K + scol;
  const unsigned short* pB1 = B + (size_t)(n0 + 128 + srow) * K + scol;
  const int wvLds = w * 512;
  const int aSlotOff = wrow * 8192;
  const int bSlotOff = (wcol >> 1) * 8192;
  const int swzc = (q * 8) ^ ((r & 7) << 3);
  const int aoff = r * 64 + swzc;
  const int boff = (wcol & 1) * 4096 + r * 64 + swzc;
  bf16x8 av[4][2], bv[4][2];
  f32x4 acc[8][4] = {};
  const int NT = K >> 6;   // K-tiles (even, >=4)
  const int NI = NT >> 1;
  // prologue: K-tile 0 full (s0-s3) + K-tile 1 B halves (s6,s7)
  g256_stage(lds, 0, pA0, 0, wvLds, K);
  g256_stage(lds, 1, pA1, 0, wvLds, K);
  g256_stage(lds, 2, pB0, 0, wvLds, K);
  g256_stage(lds, 3, pB1, 0, wvLds, K);
  g256_stage(lds, 6, pB0, 1, wvLds, K);
  g256_stage(lds, 7, pB1, 1, wvLds, K);
  asm volatile("s_waitcnt vmcnt(4)" ::: "memory");  // s0-s3 landed
  __builtin_amdgcn_s_barrier();
#pragma unroll 1
  for (int it = 0; it < NI; ++it) {
    const int ktO  = 2 * it + 1;
    const int ktE2 = (2 * it + 2 < NT) ? 2 * it + 2 : NT - 1;  // clamp (tail: dead)
    const int ktO2 = (2 * it + 3 < NT) ? 2 * it + 3 : NT - 1;
    g256_phase<0, 0, 0, true,  true,  4, false, true >(lds, aSlotOff, bSlotOff, aoff, boff, wvLds, av, bv, acc, pA0, ktO,  K);
    g256_phase<0, 0, 2, false, true,  5, false, false>(lds, aSlotOff, bSlotOff, aoff, boff, wvLds, av, bv, acc, pA1, ktO,  K);
    g256_phase<0, 1, 2, true,  false, 2, false, false>(lds, aSlotOff, bSlotOff, aoff, boff, wvLds, av, bv, acc, pB0, ktE2, K);
    g256_phase<0, 1, 0, false, false, 0, true,  false>(lds, aSlotOff, bSlotOff, aoff, boff, wvLds, av, bv, acc, pA0, ktE2, K);
    g256_phase<1, 0, 0, true,  true,  1, false, true >(lds, aSlotOff, bSlotOff, aoff, boff, wvLds, av, bv, acc, pA1, ktE2, K);
    g256_phase<1, 0, 2, false, true,  3, false, false>(lds, aSlotOff, bSlotOff, aoff, boff, wvLds, av, bv, acc, pB1, ktE2, K);
    g256_phase<1, 1, 2, true,  false, 6, false, false>(lds, aSlotOff, bSlotOff, aoff, boff, wvLds, av, bv, acc, pB0, ktO2, K);
    g256_phase<1, 1, 0, false, false, 7, true,  false>(lds, aSlotOff, bSlotOff, aoff, boff, wvLds, av, bv, acc, pB1, ktO2, K);
  }
  asm volatile("s_waitcnt vmcnt(0) lgkmcnt(0)" ::: "memory");
  // epilogue: C/D layout col = lane&15, row = (lane>>4)*4 + reg
  float* Cw = C + (size_t)(m0 + wrow * 128) * N + n0 + wcol * 64;
#pragma unroll
  for (int ii = 0; ii < 8; ++ii)
#pragma unroll
    for (int jj = 0; jj < 4; ++jj)
#pragma unroll
      for (int t = 0; t < 4; ++t)
        Cw[(size_t)(ii * 16 + q * 4 + t) * N + jj * 16 + r] = acc[ii][jj][t];
}

// -------- depthwise conv (k=3, pad=1) + SiLU, batched rolling window -------
// Old version had a 1-deep load chain (up(s) -> u0(s+1)). Now: two batches of
// 8 INDEPENDENT row loads in flight, then 8 outputs computed from registers.
// Same per-output op order -> bit-identical.
__global__ __launch_bounds__(256) void conv_silu_roll(
    const float* __restrict__ h, const float* __restrict__ Kx, const float* __restrict__ Kz,
    float* __restrict__ xb, unsigned short* __restrict__ xbbf,
    unsigned short* __restrict__ cat) {
  const int c4 = threadIdx.x << 2;          // channel group base (0..1020)
  const int bt = blockIdx.x >> 8;           // batch
  const int lt = blockIdx.x & 255;          // l-tile (16 rows each)
  const int l0 = lt << 4;
  const float* Kp; int c;
  if (c4 < 512) { Kp = Kx; c = c4; } else { Kp = Kz; c = c4 - 512; }
  const float4* K4 = (const float4*)(Kp + c * 3);  // 12 floats, 16B-aligned
  const float4 ka = K4[0], kb = K4[1], kc = K4[2];
  size_t rowbase = ((size_t)bt * 4096 + l0) * 1024 + c4;   // h/cat index, row l0
  size_t xrow    = ((size_t)bt * 4096 + l0) * 512 + c4;    // xb/xbbf index
  const float4 zero = make_float4(0.f, 0.f, 0.f, 0.f);
  float4 prev = (l0 > 0) ? *(const float4*)(h + rowbase - 1024) : zero;
  float4 cur  = *(const float4*)(h + rowbase);
#pragma unroll
  for (int half = 0; half < 2; ++half) {
    float4 nxt[8];
#pragma unroll
    for (int j = 0; j < 8; ++j) {
      const int li = l0 + half * 8 + 1 + j;   // row being loaded (l0+1..l0+16)
      nxt[j] = (li < 4096)
                   ? *(const float4*)(h + rowbase + (size_t)(half * 8 + 1 + j) * 1024)
                   : zero;
    }
#pragma unroll
    for (int sj = 0; sj < 8; ++sj) {
      const int s = half * 8 + sj;
      float4 um = prev, u0 = cur, up = nxt[sj];
      float v0 = um.x * ka.x + u0.x * ka.y + up.x * ka.z;
      float v1 = um.y * ka.w + u0.y * kb.x + up.y * kb.y;
      float v2 = um.z * kb.z + u0.z * kb.w + up.z * kc.x;
      float v3 = um.w * kc.y + u0.w * kc.z + up.w * kc.w;
      float o0 = v0 / (1.f + __expf(-v0));
      float o1 = v1 / (1.f + __expf(-v1));
      float o2 = v2 / (1.f + __expf(-v2));
      float o3 = v3 / (1.f + __expf(-v3));
      ushort4 ob;
      ob.x = f2bf(o0); ob.y = f2bf(o1); ob.z = f2bf(o2); ob.w = f2bf(o3);
      if (c4 < 512) {
        size_t xo = xrow + (size_t)s * 512;
        *(float4*)(xb + xo) = make_float4(o0, o1, o2, o3);
        *(ushort4*)(xbbf + xo) = ob;
      } else {
        *(ushort4*)(cat + rowbase + (size_t)s * 1024) = ob;
      }
      prev = cur; cur = up;
    }
  }
}

// ---------------- chunked selective scan (128 chunks x 32 steps) ----------
// delta precomputed (fused into gemm_dt128). bt/ct tiles preloaded into LDS
// (block-uniform broadcast); delta/xv loads batched 8-deep.
__global__ __launch_bounds__(256) void scan_p1(
    const float* __restrict__ delta_in, const float* __restrict__ bterm,
    const float* __restrict__ xb, const float* __restrict__ A_log,
    float* __restrict__ Aprod, float* __restrict__ Bpart) {
  __shared__ float btl[256];   // [step 0..31][s 0..7]
  int tid = threadIdx.x;
  int gid = blockIdx.x;
  int chunk = gid & 127, half = (gid >> 7) & 1, b = gid >> 8;
  int c = half * 256 + tid;
  int l0 = chunk * 32;
  btl[tid] = bterm[((size_t)b * 4096 + l0) * 8 + tid];
  float4 a0 = *(const float4*)&A_log[c * 8];
  float4 a1 = *(const float4*)&A_log[c * 8 + 4];
  float na[8] = {a0.x, a0.y, a0.z, a0.w, a1.x, a1.y, a1.z, a1.w};
#pragma unroll
  for (int s = 0; s < 8; ++s) na[s] = -(fsoftplus(na[s]) + 1e-4f);
  __syncthreads();
  size_t base = ((size_t)b * 4096 + l0) * 512 + c;
  float S[8] = {}, Ap[8] = {1.f, 1.f, 1.f, 1.f, 1.f, 1.f, 1.f, 1.f};
  for (int ib = 0; ib < 32; ib += 8) {
    float dl8[8], xv8[8];
#pragma unroll
    for (int j = 0; j < 8; ++j) {
      dl8[j] = delta_in[base + (size_t)j * 512];
      xv8[j] = xb[base + (size_t)j * 512];
    }
#pragma unroll
    for (int j = 0; j < 8; ++j) {
      float delta = dl8[j], xv = xv8[j];
      const float* bt = &btl[(ib + j) * 8];
#pragma unroll
      for (int s = 0; s < 8; ++s) {
        float dec = fminf(fmaxf(__expf(delta * na[s]), 1e-4f), 1.f);
        float btx = bt[s] * xv;
        S[s] = dec * S[s] + (btx - dec * btx);
        Ap[s] *= dec;
      }
    }
    base += (size_t)8 * 512;
  }
  size_t o = (size_t)chunk * 16384 + ((size_t)(b * 512 + c)) * 8;
  *(float4*)&Aprod[o]     = make_float4(Ap[0], Ap[1], Ap[2], Ap[3]);
  *(float4*)&Aprod[o + 4] = make_float4(Ap[4], Ap[5], Ap[6], Ap[7]);
  *(float4*)&Bpart[o]     = make_float4(S[0], S[1], S[2], S[3]);
  *(float4*)&Bpart[o + 4] = make_float4(S[4], S[5], S[6], S[7]);
}

// 256 blocks x 64 threads: same 16384 series, spread over all 256 CUs.
__global__ __launch_bounds__(64) void scan_p2(
    const float* __restrict__ Aprod, const float* __restrict__ Bpart,
    float* __restrict__ initst) {
  int t = blockIdx.x * 64 + threadIdx.x;  // 16384 threads: one (b,c,s)
  float st = 0.f;
  for (int cb = 0; cb < 128; cb += 8) {
    float a[8], bb[8];
#pragma unroll
    for (int j = 0; j < 8; ++j) {
      size_t o = (size_t)(cb + j) * 16384 + t;
      a[j] = Aprod[o]; bb[j] = Bpart[o];
    }
#pragma unroll
    for (int j = 0; j < 8; ++j) {
      size_t o = (size_t)(cb + j) * 16384 + t;
      initst[o] = st;
      st = a[j] * st + bb[j];
    }
  }
}

__global__ __launch_bounds__(256) void scan_p3(
    const float* __restrict__ delta_in, const float* __restrict__ bterm,
    const float* __restrict__ cterm, const float* __restrict__ xb,
    const float* __restrict__ A_log, const float* __restrict__ Dp,
    const float* __restrict__ initst, unsigned short* __restrict__ cat) {
  __shared__ float btl[256], ctl[256];   // [step 0..31][s 0..7]
  int tid = threadIdx.x;
  int gid = blockIdx.x;
  int chunk = gid & 127, half = (gid >> 7) & 1, b = gid >> 8;
  int c = half * 256 + tid;
  int l0 = chunk * 32;
  {
    size_t bb = ((size_t)b * 4096 + l0) * 8 + tid;
    btl[tid] = bterm[bb];
    ctl[tid] = cterm[bb];
  }
  float4 a0 = *(const float4*)&A_log[c * 8];
  float4 a1 = *(const float4*)&A_log[c * 8 + 4];
  float na[8] = {a0.x, a0.y, a0.z, a0.w, a1.x, a1.y, a1.z, a1.w};
#pragma unroll
  for (int s = 0; s < 8; ++s) na[s] = -(fsoftplus(na[s]) + 1e-4f);
  float Dv = Dp[c];
  size_t o = (size_t)chunk * 16384 + ((size_t)(b * 512 + c)) * 8;
  float4 s0 = *(const float4*)&initst[o];
  float4 s1 = *(const float4*)&initst[o + 4];
  float S[8] = {s0.x, s0.y, s0.z, s0.w, s1.x, s1.y, s1.z, s1.w};
  __syncthreads();
  size_t base  = ((size_t)b * 4096 + l0) * 512 + c;
  size_t cbase = ((size_t)b * 4096 + l0) * 1024 + c;   // y -> cat[..., :512]
  for (int ib = 0; ib < 32; ib += 8) {
    float dl8[8], xv8[8];
#pragma unroll
    for (int j = 0; j < 8; ++j) {
      dl8[j] = delta_in[base + (size_t)j * 512];
      xv8[j] = xb[base + (size_t)j * 512];
    }
#pragma unroll
    for (int j = 0; j < 8; ++j) {
      float delta = dl8[j], xv = xv8[j];
      const float* bt = &btl[(ib + j) * 8];
      const float* ct = &ctl[(ib + j) * 8];
      float acc = Dv * xv;
#pragma unroll
      for (int s = 0; s < 8; ++s) {
        float dec = fminf(fmaxf(__expf(delta * na[s]), 1e-4f), 1.f);
        float btx = bt[s] * xv;
        S[s] = dec * S[s] + (btx - dec * btx);
        acc += S[s] * ct[s];
      }
      cat[cbase + (size_t)(ib + j) * 1024] = f2bf(acc);
    }
    base += (size_t)8 * 512;
  }
}

// ---------------- launch ----------------
extern "C" void kernel_launch(void* const* d_in, const int* in_sizes, int n_in,
                              void* d_out, int out_size, void* d_ws, size_t ws_size,
                              hipStream_t stream) {
  (void)in_sizes; (void)n_in; (void)out_size; (void)ws_size;
  const float* x       = (const float*)d_in[0];
  const float* W_in    = (const float*)d_in[1];
  const float* Kx      = (const float*)d_in[2];
  const float* Kz      = (const float*)d_in[3];
  const float* W_xproj = (const float*)d_in[4];
  const float* W_dt    = (const float*)d_in[5];
  const float* b_dt    = (const float*)d_in[6];
  const float* A_log   = (const float*)d_in[7];
  const float* Dp      = (const float*)d_in[8];
  const float* W_out   = (const float*)d_in[9];
  float* out = (float*)d_out;

  // workspace layout (133.4 MB) with dead-buffer overlays
  char* w = (char*)d_ws;
  unsigned short* xbf  = (unsigned short*)(w);               // 33.5MB x bf16; reused as cat
  float* xb    = (float*)(w + 33554432);                     // 33.5MB fp32 xb (scan)
  float* draw  = (float*)(w + 67108864);                     // 33.5MB delta (fused softplus)
  float* bterm = (float*)(w + 100663296);                    // 0.5MB
  float* cterm = (float*)(w + 101187584);                    // 0.5MB
  float* Aprod = (float*)(w + 101711872);                    // 8MB [chunk][bcs]
  float* Bpart = (float*)(w + 110100480);                    // 8MB
  float* initst = (float*)(w + 118489088);                   // 8MB
  unsigned short* winbf  = (unsigned short*)(w + 126877696); // 2MB
  unsigned short* woutbf = (unsigned short*)(w + 128974848); // 2MB
  unsigned short* dtr    = (unsigned short*)(w + 131072000); // 2MB (16384x64 bf16)
  unsigned short* wxp_bf = (unsigned short*)(w + 133169152); // 128KB
  unsigned short* wd_bf  = (unsigned short*)(w + 133300224); // 64KB  (end 133365760)
  unsigned short* xbbf = (unsigned short*)Aprod;             // 16.8MB overlay; dead before scan
  float* h = out;  // d_out doubles as h scratch (fully rewritten by final GEMM)

  // all fp32->bf16 conversions in one launch (4 float4/thread)
  prep_all<<<4680, 256, 0, stream>>>(x, W_in, W_out, W_dt, W_xproj,
                                     xbf, winbf, woutbf, wd_bf, wxp_bf);

  // big GEMMs: 256x256 8-phase kernel, grid = (16384/256)*(1024/256) = 256
  gemm256_bt<<<256, 512, 0, stream>>>(xbf, winbf, h, 16384, 1024, 1024);

  conv_silu_roll<<<1024, 256, 0, stream>>>(h, Kx, Kz, xb, xbbf, xbf /*cat*/);

  // proj GEMM with fused dtr/bterm/cterm epilogue, 64-row tiles (full GPU)
  gemm_proj64<<<256, 256, 0, stream>>>(xbbf, wxp_bf, dtr, bterm, cterm, 16384, 128, 512);
  // dt GEMM with fused softplus+clip epilogue -> delta (into draw buffer)
  gemm_dt128<<<dim3(128, 4), 256, 0, stream>>>(dtr, wd_bf, b_dt, draw, 16384, 512, 64);

  scan_p1<<<1024, 256, 0, stream>>>(draw, bterm, xb, A_log, Aprod, Bpart);
  scan_p2<<<256, 64, 0, stream>>>(Aprod, Bpart, initst);
  scan_p3<<<1024, 256, 0, stream>>>(draw, bterm, cterm, xb, A_log, Dp, initst, xbf /*cat*/);

  gemm256_bt<<<256, 512, 0, stream>>>(xbf, woutbf, out, 16384, 1024, 1024);
}